// Round 2
// baseline (78.210 us; speedup 1.0000x reference)
//
#include <hip/hip_runtime.h>

#define TT 256
#define HH 512
#define WW 512
#define LOG2E 1.44269504088896340736f
#define KS (100.0f * LOG2E)
#define STEP (1.0f / 511.0f)
#define TILE_W 64
#define TILE_H 4
#define SKIP_LOG2 -40.0f   // skip triangle for tile if mask provably < 2^-40

// ws layout (floats):
//   [0 .. 16*TT)      : per-triangle packed constants, 4 x float4 each:
//     q0 = (Dy0, Dx0, C0, Dy1)   (edge consts pre-scaled by SHARPNESS*log2e)
//     q1 = (Dx1, C1, Dy2, Dx2)
//     q2 = (C2, expd, expd*EPS, 0)
//     q3 = (cr, cg, cb, 0)
//   [16*TT .. 16*TT+4): eps baseline (S_eps, Sr_eps, Sg_eps, Sb_eps)
__global__ __launch_bounds__(256) void tri_setup(
        const float* __restrict__ verts,
        const float* __restrict__ colors,
        const float* __restrict__ depth,
        float* __restrict__ ws) {
    int t = threadIdx.x;
    float4* tri = (float4*)ws;

    float v0x = verts[t * 6 + 0], v0y = verts[t * 6 + 1];
    float v1x = verts[t * 6 + 2], v1y = verts[t * 6 + 3];
    float v2x = verts[t * 6 + 4], v2y = verts[t * 6 + 5];

    // edge(p, va, vb) = px*dy - py*dx + (ay*dx - ax*dy)
    float dx0 = v1x - v0x, dy0 = v1y - v0y;
    float dx1 = v2x - v1x, dy1 = v2y - v1y;
    float dx2 = v0x - v2x, dy2 = v0y - v2y;
    float c0 = v0y * dx0 - v0x * dy0;
    float c1 = v1y * dx1 - v1x * dy1;
    float c2 = v2y * dx2 - v2x * dy2;

    float expd = __builtin_amdgcn_exp2f(depth[t] * LOG2E);
    float cr = colors[t * 3 + 0], cg = colors[t * 3 + 1], cb = colors[t * 3 + 2];
    float se = expd * 1e-6f;

    tri[t * 4 + 0] = make_float4(KS * dy0, KS * dx0, KS * c0, KS * dy1);
    tri[t * 4 + 1] = make_float4(KS * dx1, KS * c1, KS * dy2, KS * dx2);
    tri[t * 4 + 2] = make_float4(KS * c2, expd, se, 0.0f);
    tri[t * 4 + 3] = make_float4(cr, cg, cb, 0.0f);

    // deterministic tree-reduction of the eps baseline
    __shared__ float red[256];
    float vals[4] = {se, se * cr, se * cg, se * cb};
    #pragma unroll
    for (int c = 0; c < 4; ++c) {
        red[t] = vals[c];
        __syncthreads();
        for (int s = 128; s > 0; s >>= 1) {
            if (t < s) red[t] += red[t + s];
            __syncthreads();
        }
        if (t == 0) ws[16 * TT + c] = red[0];
        __syncthreads();
    }
}

__global__ __launch_bounds__(256) void tri_render(
        const float* __restrict__ ws,
        float* __restrict__ out) {
    const float4* tri = (const float4*)ws;
    const float* baseline = ws + 16 * TT;

    __shared__ int s_list[TT];
    __shared__ int s_meta[4];

    int tid = threadIdx.x;
    int b = blockIdx.x;
    int tx = b & 7;          // 8 tile columns of 64 px
    int ty = b >> 3;         // 128 tile rows of 4 px

    // ---------- binning: thread t corner-tests triangle t ----------
    {
        float x0 = (float)(tx * TILE_W) * STEP;
        float y0 = (float)(ty * TILE_H) * STEP;
        float tw = (float)(TILE_W - 1) * STEP;
        float th = (float)(TILE_H - 1) * STEP;

        int t = tid;
        float4 q0 = tri[t * 4 + 0];
        float4 q1 = tri[t * 4 + 1];
        float4 q2 = tri[t * 4 + 2];

        // E(x,y) = x*Dy - y*Dx + C; max over tile = corner max (affine)
        float e0 = fmaf(x0, q0.x, fmaf(-y0, q0.y, q0.z))
                 + fmaxf(tw * q0.x, 0.0f) + fmaxf(-th * q0.y, 0.0f);
        float e1 = fmaf(x0, q0.w, fmaf(-y0, q1.x, q1.y))
                 + fmaxf(tw * q0.w, 0.0f) + fmaxf(-th * q1.x, 0.0f);
        float e2 = fmaf(x0, q1.z, fmaf(-y0, q1.w, q2.x))
                 + fmaxf(tw * q1.z, 0.0f) + fmaxf(-th * q1.w, 0.0f);
        float score = fminf(fminf(e0, e1), e2);
        bool hit = score > SKIP_LOG2;

        unsigned long long mask = __ballot(hit);
        int wv = tid >> 6;
        int lane = tid & 63;
        if (lane == 0) s_meta[wv] = __popcll(mask);
        __syncthreads();
        int base = 0;
        #pragma unroll
        for (int w = 0; w < 4; ++w)
            base += (w < wv) ? s_meta[w] : 0;
        if (hit) {
            int pos = base + __popcll(mask & ((1ull << lane) - 1ull));
            s_list[pos] = t;
        }
    }
    __syncthreads();
    int cnt = s_meta[0] + s_meta[1] + s_meta[2] + s_meta[3];
    cnt = __builtin_amdgcn_readfirstlane(cnt);

    // ---------- main loop over binned triangles ----------
    int lx = tid & 63, ly = tid >> 6;
    int gx = tx * TILE_W + lx;
    int gy = ty * TILE_H + ly;
    float px = (float)gx * STEP;
    float py = (float)gy * STEP;

    float sum = baseline[0];
    float r = baseline[1], g = baseline[2], bl = baseline[3];

    for (int j = 0; j < cnt; ++j) {
        int idx = __builtin_amdgcn_readfirstlane(s_list[j]);
        const float4* q = tri + idx * 4;
        float4 q0 = q[0];
        float4 q1 = q[1];
        float4 q2 = q[2];
        float4 q3 = q[3];

        float E0 = fmaf(px, q0.x, fmaf(-py, q0.y, q0.z));
        float E1 = fmaf(px, q0.w, fmaf(-py, q1.x, q1.y));
        float E2 = fmaf(px, q1.z, fmaf(-py, q1.w, q2.x));

        // mask = 1/((1+2^-E0)(1+2^-E1)(1+2^-E2)); overflow -> inf -> rcp -> 0
        float a0 = 1.0f + __builtin_amdgcn_exp2f(-E0);
        float a1 = 1.0f + __builtin_amdgcn_exp2f(-E1);
        float a2 = 1.0f + __builtin_amdgcn_exp2f(-E2);
        float m = __builtin_amdgcn_rcpf(a0 * a1 * a2);

        float s = q2.y * m;      // expd * mask   (eps part already in baseline)
        sum += s;
        r = fmaf(s, q3.x, r);
        g = fmaf(s, q3.y, g);
        bl = fmaf(s, q3.z, bl);
    }

    float inv = 1.0f / sum;
    int pix = gy * WW + gx;
    out[pix]               = r * inv;
    out[HH * WW + pix]     = g * inv;
    out[2 * HH * WW + pix] = bl * inv;
}

extern "C" void kernel_launch(void* const* d_in, const int* in_sizes, int n_in,
                              void* d_out, int out_size, void* d_ws, size_t ws_size,
                              hipStream_t stream) {
    const float* verts  = (const float*)d_in[0];
    const float* colors = (const float*)d_in[1];
    const float* depth  = (const float*)d_in[2];
    float* out = (float*)d_out;
    float* ws  = (float*)d_ws;   // 16 KiB + 16 B

    tri_setup<<<dim3(1), dim3(256), 0, stream>>>(verts, colors, depth, ws);
    tri_render<<<dim3((WW / TILE_W) * (HH / TILE_H)), dim3(256), 0, stream>>>(ws, out);
}

// Round 3
// 42.247 us; speedup vs baseline: 1.8512x; 1.8512x over previous
//
#include <hip/hip_runtime.h>

#define TT 256
#define HH 512
#define WW 512
#define LOG2E 1.44269504088896340736f
#define KS (100.0f * LOG2E)
#define STEP (1.0f / 511.0f)
#define RUN 8      // consecutive y-pixels per thread
#define CHUNK 64   // triangles per wave (4 waves cover all 256)

// ws layout (floats):
//  [0 .. 16*TT)     : per-triangle 16-float record
//    {Dy0,Dx0,C0, Dy1,Dx1,C1, Dy2,Dx2,C2, k0,k1,k2, expd, cr,cg,cb}
//    E_i(x,y) = x*Dy_i - y*Dx_i + C_i (pre-scaled by SHARPNESS*log2e)
//    u_i = 2^-E_i ; step y -> y+STEP multiplies u_i by k_i = 2^(STEP*Dx_i)
//  [16*TT .. +4)    : eps baseline (S, Sr, Sg, Sb)
__global__ __launch_bounds__(256) void tri_setup(
        const float* __restrict__ verts,
        const float* __restrict__ colors,
        const float* __restrict__ depth,
        float* __restrict__ ws) {
    int t = threadIdx.x;

    float v0x = verts[t * 6 + 0], v0y = verts[t * 6 + 1];
    float v1x = verts[t * 6 + 2], v1y = verts[t * 6 + 3];
    float v2x = verts[t * 6 + 4], v2y = verts[t * 6 + 5];

    float dx0 = v1x - v0x, dy0 = v1y - v0y;
    float dx1 = v2x - v1x, dy1 = v2y - v1y;
    float dx2 = v0x - v2x, dy2 = v0y - v2y;
    float c0 = v0y * dx0 - v0x * dy0;
    float c1 = v1y * dx1 - v1x * dy1;
    float c2 = v2y * dx2 - v2x * dy2;

    float expd = __builtin_amdgcn_exp2f(depth[t] * LOG2E);
    float cr = colors[t * 3 + 0], cg = colors[t * 3 + 1], cb = colors[t * 3 + 2];
    float se = expd * 1e-6f;

    float* f = ws + t * 16;
    f[0] = KS * dy0;  f[1] = KS * dx0;  f[2] = KS * c0;
    f[3] = KS * dy1;  f[4] = KS * dx1;  f[5] = KS * c1;
    f[6] = KS * dy2;  f[7] = KS * dx2;  f[8] = KS * c2;
    f[9]  = __builtin_amdgcn_exp2f(STEP * (KS * dx0));
    f[10] = __builtin_amdgcn_exp2f(STEP * (KS * dx1));
    f[11] = __builtin_amdgcn_exp2f(STEP * (KS * dx2));
    f[12] = expd; f[13] = cr; f[14] = cg; f[15] = cb;

    // deterministic tree-reduction of the eps baseline
    __shared__ float red[256];
    float vals[4] = {se, se * cr, se * cg, se * cb};
    #pragma unroll
    for (int c = 0; c < 4; ++c) {
        red[t] = vals[c];
        __syncthreads();
        for (int s = 128; s > 0; s >>= 1) {
            if (t < s) red[t] += red[t + s];
            __syncthreads();
        }
        if (t == 0) ws[16 * TT + c] = red[0];
        __syncthreads();
    }
}

__global__ __launch_bounds__(256) void tri_render(
        const float* __restrict__ ws,
        float* __restrict__ out) {
    __shared__ float4 s_part[4][RUN][64];   // 32 KiB

    int tid  = threadIdx.x;
    int lane = tid & 63;
    int wave = __builtin_amdgcn_readfirstlane(tid >> 6);

    int bx = blockIdx.x & 7;    // 8 x-strips of 64
    int by = blockIdx.x >> 3;   // 64 y-runs of 8

    float px  = (float)(bx * 64 + lane) * STEP;
    float py0 = (float)(by * RUN) * STEP;

    float acc[RUN][4];
    #pragma unroll
    for (int i = 0; i < RUN; ++i) {
        acc[i][0] = 0.0f; acc[i][1] = 0.0f; acc[i][2] = 0.0f; acc[i][3] = 0.0f;
    }

    const float* tbase = ws + wave * (CHUNK * 16);

    for (int j = 0; j < CHUNK; ++j) {
        const float* tp = tbase + (j << 4);
        float Dy0 = tp[0],  Dx0 = tp[1],  C0 = tp[2];
        float Dy1 = tp[3],  Dx1 = tp[4],  C1 = tp[5];
        float Dy2 = tp[6],  Dx2 = tp[7],  C2 = tp[8];
        float k0  = tp[9],  k1  = tp[10], k2 = tp[11];
        float expd = tp[12], cr = tp[13], cg = tp[14], cb = tp[15];

        // u_i = 2^(-E_i) at (px, py0); -E = py*Dx - px*Dy - C
        float n0 = py0 * Dx0;  n0 = n0 - C0;  n0 = fmaf(-px, Dy0, n0);
        float n1 = py0 * Dx1;  n1 = n1 - C1;  n1 = fmaf(-px, Dy1, n1);
        float n2 = py0 * Dx2;  n2 = n2 - C2;  n2 = fmaf(-px, Dy2, n2);
        float u0 = __builtin_amdgcn_exp2f(n0);
        float u1 = __builtin_amdgcn_exp2f(n1);
        float u2 = __builtin_amdgcn_exp2f(n2);

        #pragma unroll
        for (int i = 0; i < RUN / 2; ++i) {
            // pixel A at y-index 2i
            float a  = u1 + 1.0f;
            float PA = fmaf(u0, a, a);      // (1+u0)(1+u1)
            PA = fmaf(u2, PA, PA);          // *(1+u2)
            PA = fminf(PA, 1e18f);          // pair-product overflow guard
            u0 *= k0; u1 *= k1; u2 *= k2;   // advance to y-index 2i+1
            // pixel B at y-index 2i+1
            a = u1 + 1.0f;
            float PB = fmaf(u0, a, a);
            PB = fmaf(u2, PB, PB);
            PB = fminf(PB, 1e18f);
            if (i != RUN / 2 - 1) { u0 *= k0; u1 *= k1; u2 *= k2; }

            float rinv = __builtin_amdgcn_rcpf(PA * PB);  // one rcp / 2 px
            float wA = rinv * PB * expd;    // expd * mask_A
            float wB = rinv * PA * expd;

            acc[2*i][0]   += wA;
            acc[2*i+1][0] += wB;
            acc[2*i][1]   = fmaf(wA, cr, acc[2*i][1]);
            acc[2*i+1][1] = fmaf(wB, cr, acc[2*i+1][1]);
            acc[2*i][2]   = fmaf(wA, cg, acc[2*i][2]);
            acc[2*i+1][2] = fmaf(wB, cg, acc[2*i+1][2]);
            acc[2*i][3]   = fmaf(wA, cb, acc[2*i][3]);
            acc[2*i+1][3] = fmaf(wB, cb, acc[2*i+1][3]);
        }
    }

    #pragma unroll
    for (int i = 0; i < RUN; ++i)
        s_part[wave][i][lane] = make_float4(acc[i][0], acc[i][1], acc[i][2], acc[i][3]);
    __syncthreads();

    // finalize: 256 threads -> 512 pixels (2 each)
    const float* base = ws + 16 * TT;
    float b0 = base[0], b1 = base[1], b2 = base[2], b3 = base[3];

    #pragma unroll
    for (int pi = 0; pi < 2; ++pi) {
        int p = tid + pi * 256;
        int i = p >> 6, l = p & 63;
        float4 v0 = s_part[0][i][l];
        float4 v1 = s_part[1][i][l];
        float4 v2 = s_part[2][i][l];
        float4 v3 = s_part[3][i][l];
        float sum = b0 + v0.x + v1.x + v2.x + v3.x;
        float r   = b1 + v0.y + v1.y + v2.y + v3.y;
        float g   = b2 + v0.z + v1.z + v2.z + v3.z;
        float bch = b3 + v0.w + v1.w + v2.w + v3.w;
        float inv = 1.0f / sum;
        int gy = by * RUN + i;
        int gx = bx * 64 + l;
        int pix = gy * WW + gx;
        out[pix]               = r   * inv;
        out[HH * WW + pix]     = g   * inv;
        out[2 * HH * WW + pix] = bch * inv;
    }
}

extern "C" void kernel_launch(void* const* d_in, const int* in_sizes, int n_in,
                              void* d_out, int out_size, void* d_ws, size_t ws_size,
                              hipStream_t stream) {
    const float* verts  = (const float*)d_in[0];
    const float* colors = (const float*)d_in[1];
    const float* depth  = (const float*)d_in[2];
    float* out = (float*)d_out;
    float* ws  = (float*)d_ws;   // 16 KiB + 16 B

    tri_setup<<<dim3(1), dim3(256), 0, stream>>>(verts, colors, depth, ws);
    tri_render<<<dim3((WW / 64) * (HH / RUN)), dim3(256), 0, stream>>>(ws, out);
}

// Round 4
// 34.790 us; speedup vs baseline: 2.2480x; 1.2143x over previous
//
#include <hip/hip_runtime.h>

#define TT 256
#define HH 512
#define WW 512
#define LOG2E 1.44269504088896340736f
#define KS (100.0f * LOG2E)
#define STEP (1.0f / 511.0f)
#define RUN 8      // consecutive y-pixels per thread
#define NW 8       // waves per block
#define CHUNK 32   // triangles per wave (8 waves cover all 256)

// ws layout (floats):
//  [0 .. 16*TT)   : per-triangle 16-float record
//    {Dy0,Dx0,C0, Dy1,Dx1,C1, Dy2,Dx2,C2, k0,k1,k2, expd, expd*cr, expd*cg, expd*cb}
//    E_i(x,y) = x*Dy_i - y*Dx_i + C_i (pre-scaled by SHARPNESS*log2e)
//    u_i = 2^-E_i ; y -> y+STEP multiplies u_i by k_i = 2^(STEP*Dx_i)
//  [16*TT .. +4)  : eps baseline (S, Sr, Sg, Sb)
__global__ __launch_bounds__(256) void tri_setup(
        const float* __restrict__ verts,
        const float* __restrict__ colors,
        const float* __restrict__ depth,
        float* __restrict__ ws) {
    int t = threadIdx.x;

    float v0x = verts[t * 6 + 0], v0y = verts[t * 6 + 1];
    float v1x = verts[t * 6 + 2], v1y = verts[t * 6 + 3];
    float v2x = verts[t * 6 + 4], v2y = verts[t * 6 + 5];

    float dx0 = v1x - v0x, dy0 = v1y - v0y;
    float dx1 = v2x - v1x, dy1 = v2y - v1y;
    float dx2 = v0x - v2x, dy2 = v0y - v2y;
    float c0 = v0y * dx0 - v0x * dy0;
    float c1 = v1y * dx1 - v1x * dy1;
    float c2 = v2y * dx2 - v2x * dy2;

    float expd = __builtin_amdgcn_exp2f(depth[t] * LOG2E);
    float cr = colors[t * 3 + 0], cg = colors[t * 3 + 1], cb = colors[t * 3 + 2];
    float ecr = expd * cr, ecg = expd * cg, ecb = expd * cb;

    float* f = ws + t * 16;
    f[0] = KS * dy0;  f[1] = KS * dx0;  f[2] = KS * c0;
    f[3] = KS * dy1;  f[4] = KS * dx1;  f[5] = KS * c1;
    f[6] = KS * dy2;  f[7] = KS * dx2;  f[8] = KS * c2;
    f[9]  = __builtin_amdgcn_exp2f(STEP * (KS * dx0));
    f[10] = __builtin_amdgcn_exp2f(STEP * (KS * dx1));
    f[11] = __builtin_amdgcn_exp2f(STEP * (KS * dx2));
    f[12] = expd; f[13] = ecr; f[14] = ecg; f[15] = ecb;

    // deterministic single-pass float4 tree reduction of the eps baseline
    __shared__ float4 red[256];
    red[t] = make_float4(expd * 1e-6f, ecr * 1e-6f, ecg * 1e-6f, ecb * 1e-6f);
    __syncthreads();
    for (int s = 128; s > 0; s >>= 1) {
        if (t < s) {
            float4 a = red[t], b = red[t + s];
            red[t] = make_float4(a.x + b.x, a.y + b.y, a.z + b.z, a.w + b.w);
        }
        __syncthreads();
    }
    if (t == 0) {
        ws[16 * TT + 0] = red[0].x;
        ws[16 * TT + 1] = red[0].y;
        ws[16 * TT + 2] = red[0].z;
        ws[16 * TT + 3] = red[0].w;
    }
}

__global__ __launch_bounds__(512) void tri_render(
        const float* __restrict__ ws,
        float* __restrict__ out) {
    __shared__ float4 s_part[4][RUN][64];   // 32 KiB

    int tid  = threadIdx.x;
    int lane = tid & 63;
    int wave = __builtin_amdgcn_readfirstlane(tid >> 6);

    int bx = blockIdx.x & 7;    // 8 x-strips of 64
    int by = blockIdx.x >> 3;   // 64 y-runs of 8

    float px  = (float)(bx * 64 + lane) * STEP;
    float py0 = (float)(by * RUN) * STEP;

    float acc[RUN][4];
    #pragma unroll
    for (int i = 0; i < RUN; ++i) {
        acc[i][0] = 0.0f; acc[i][1] = 0.0f; acc[i][2] = 0.0f; acc[i][3] = 0.0f;
    }

    const float* tbase = ws + wave * (CHUNK * 16);

    #pragma unroll 2
    for (int j = 0; j < CHUNK; ++j) {
        const float* tp = tbase + (j << 4);
        float Dy0 = tp[0],  Dx0 = tp[1],  C0 = tp[2];
        float Dy1 = tp[3],  Dx1 = tp[4],  C1 = tp[5];
        float Dy2 = tp[6],  Dx2 = tp[7],  C2 = tp[8];
        float k0  = tp[9],  k1  = tp[10], k2 = tp[11];
        float expd = tp[12], ecr = tp[13], ecg = tp[14], ecb = tp[15];

        // u_i = 2^(-E_i) at (px, py0); -E = py*Dx - px*Dy - C
        float n0 = fmaf(py0, Dx0, -C0);  n0 = fmaf(-px, Dy0, n0);
        float n1 = fmaf(py0, Dx1, -C1);  n1 = fmaf(-px, Dy1, n1);
        float n2 = fmaf(py0, Dx2, -C2);  n2 = fmaf(-px, Dy2, n2);
        float u0 = __builtin_amdgcn_exp2f(n0);
        float u1 = __builtin_amdgcn_exp2f(n1);
        float u2 = __builtin_amdgcn_exp2f(n2);

        #pragma unroll
        for (int i = 0; i < RUN / 2; ++i) {
            // pixel A at y-index 2i
            float a  = u1 + 1.0f;
            float PA = fmaf(u0, a, a);      // (1+u0)(1+u1)
            PA = fmaf(u2, PA, PA);          // *(1+u2)
            PA = fminf(PA, 1e18f);          // pair-product overflow guard
            u0 *= k0; u1 *= k1; u2 *= k2;   // advance to y-index 2i+1
            // pixel B at y-index 2i+1
            a = u1 + 1.0f;
            float PB = fmaf(u0, a, a);
            PB = fmaf(u2, PB, PB);
            PB = fminf(PB, 1e18f);
            if (i != RUN / 2 - 1) { u0 *= k0; u1 *= k1; u2 *= k2; }

            float rinv = __builtin_amdgcn_rcpf(PA * PB);  // one rcp / 2 px
            float wA = rinv * PB;           // mask_A
            float wB = rinv * PA;           // mask_B

            acc[2*i][0]   = fmaf(wA, expd, acc[2*i][0]);
            acc[2*i+1][0] = fmaf(wB, expd, acc[2*i+1][0]);
            acc[2*i][1]   = fmaf(wA, ecr,  acc[2*i][1]);
            acc[2*i+1][1] = fmaf(wB, ecr,  acc[2*i+1][1]);
            acc[2*i][2]   = fmaf(wA, ecg,  acc[2*i][2]);
            acc[2*i+1][2] = fmaf(wB, ecg,  acc[2*i+1][2]);
            acc[2*i][3]   = fmaf(wA, ecb,  acc[2*i][3]);
            acc[2*i+1][3] = fmaf(wB, ecb,  acc[2*i+1][3]);
        }
    }

    // two-stage deterministic reduction across the 8 waves
    if (wave >= 4) {
        #pragma unroll
        for (int i = 0; i < RUN; ++i)
            s_part[wave - 4][i][lane] =
                make_float4(acc[i][0], acc[i][1], acc[i][2], acc[i][3]);
    }
    __syncthreads();
    if (wave < 4) {
        #pragma unroll
        for (int i = 0; i < RUN; ++i) {
            float4 v = s_part[wave][i][lane];
            v.x += acc[i][0]; v.y += acc[i][1];
            v.z += acc[i][2]; v.w += acc[i][3];
            s_part[wave][i][lane] = v;
        }
    }
    __syncthreads();

    // finalize: 512 threads -> 512 pixels
    const float* base = ws + 16 * TT;
    float b0 = base[0], b1 = base[1], b2 = base[2], b3 = base[3];

    int i = tid >> 6, l = tid & 63;
    float4 v0 = s_part[0][i][l];
    float4 v1 = s_part[1][i][l];
    float4 v2 = s_part[2][i][l];
    float4 v3 = s_part[3][i][l];
    float sum = b0 + ((v0.x + v1.x) + (v2.x + v3.x));
    float r   = b1 + ((v0.y + v1.y) + (v2.y + v3.y));
    float g   = b2 + ((v0.z + v1.z) + (v2.z + v3.z));
    float bch = b3 + ((v0.w + v1.w) + (v2.w + v3.w));
    float inv = 1.0f / sum;
    int gy = by * RUN + i;
    int gx = bx * 64 + l;
    int pix = gy * WW + gx;
    out[pix]               = r   * inv;
    out[HH * WW + pix]     = g   * inv;
    out[2 * HH * WW + pix] = bch * inv;
}

extern "C" void kernel_launch(void* const* d_in, const int* in_sizes, int n_in,
                              void* d_out, int out_size, void* d_ws, size_t ws_size,
                              hipStream_t stream) {
    const float* verts  = (const float*)d_in[0];
    const float* colors = (const float*)d_in[1];
    const float* depth  = (const float*)d_in[2];
    float* out = (float*)d_out;
    float* ws  = (float*)d_ws;   // 16 KiB + 16 B

    tri_setup<<<dim3(1), dim3(256), 0, stream>>>(verts, colors, depth, ws);
    tri_render<<<dim3((WW / 64) * (HH / RUN)), dim3(512), 0, stream>>>(ws, out);
}